// Round 1
// baseline (328.063 us; speedup 1.0000x reference)
//
#include <hip/hip_runtime.h>
#include <hip/hip_bf16.h>

typedef __attribute__((ext_vector_type(8))) short bf16x8;
typedef __attribute__((ext_vector_type(4))) float f32x4;

constexpr int VOCAB = 50257;
constexpr int SMALL = 512;
constexpr int LARGE = 1024;
constexpr int NTOK  = 4 * 2048;  // 8192

static __device__ __forceinline__ unsigned short f2bf(float f) {
    __hip_bfloat16 h = __float2bfloat16(f);  // RNE
    return *reinterpret_cast<unsigned short*>(&h);
}

// Kernel 1: per-token gather. out[t, 0:512] = W[id] + R[id, 0:512]; A_bf16[t] = bf16(W[id]).
// 128 threads per token, float4 per thread. Grid = NTOK*128/256 blocks of 256.
__global__ __launch_bounds__(256) void k_gather(const int* __restrict__ ids,
                                                const float* __restrict__ weight,
                                                const float* __restrict__ residual,
                                                float* __restrict__ out,
                                                unsigned short* __restrict__ a_bf16) {
    int i  = blockIdx.x * 256 + threadIdx.x;   // 0 .. NTOK*128-1
    int t  = i >> 7;                            // token
    int c  = (i & 127) << 2;                    // column (x4)
    int id = ids[t];
    const float4 w = *reinterpret_cast<const float4*>(weight   + (size_t)id * SMALL + c);
    const float4 r = *reinterpret_cast<const float4*>(residual + (size_t)id * LARGE + c);
    float4 o;
    o.x = w.x + r.x; o.y = w.y + r.y; o.z = w.z + r.z; o.w = w.w + r.w;
    *reinterpret_cast<float4*>(out + (size_t)t * LARGE + c) = o;
    ushort4 a;
    a.x = f2bf(w.x); a.y = f2bf(w.y); a.z = f2bf(w.z); a.w = f2bf(w.w);
    *reinterpret_cast<ushort4*>(a_bf16 + (size_t)t * SMALL + c) = a;
}

// Kernel 2: coeffs (512x512 f32, row-major j,k) -> bf16 same layout.
__global__ __launch_bounds__(256) void k_cvt_coeffs(const float* __restrict__ coeffs,
                                                    unsigned short* __restrict__ b_bf16) {
    int i = blockIdx.x * 256 + threadIdx.x;    // 0 .. 512*128-1
    int e = i << 2;
    const float4 cvec = *reinterpret_cast<const float4*>(coeffs + e);
    ushort4 b;
    b.x = f2bf(cvec.x); b.y = f2bf(cvec.y); b.z = f2bf(cvec.z); b.w = f2bf(cvec.w);
    *reinterpret_cast<ushort4*>(b_bf16 + e) = b;
}

// Kernel 3: GEMM out[t, 512+j] = sum_k A[t,k]*C[j,k] + R[id, 512+j]
// M=8192 (tokens), N=512 (j), K=512. Tile 128(M) x 64(N), 4 waves, each wave 32x64.
// Fragments loaded straight from global (A: 8MB, B: 0.5MB -> L2-resident).
__global__ __launch_bounds__(256) void k_gemm(const int* __restrict__ ids,
                                              const unsigned short* __restrict__ A,
                                              const unsigned short* __restrict__ B,
                                              const float* __restrict__ residual,
                                              float* __restrict__ out) {
    const int wid  = threadIdx.x >> 6;   // 0..3
    const int lane = threadIdx.x & 63;
    const int bm   = blockIdx.x >> 3;    // 0..63  (M blocks of 128)
    const int bn   = blockIdx.x & 7;     // 0..7   (N blocks of 64)
    const int row0 = bm * 128 + wid * 32;
    const int col0 = bn * 64;
    const int lr   = lane & 15;          // A row / B col within fragment
    const int lk   = (lane >> 4) * 8;    // k offset within fragment

    f32x4 acc[2][4] = {};

    const unsigned short* pa0 = A + (size_t)(row0 + lr) * SMALL + lk;
    const unsigned short* pa1 = A + (size_t)(row0 + 16 + lr) * SMALL + lk;
    const unsigned short* pb  = B + (size_t)(col0 + lr) * SMALL + lk;

    for (int k0 = 0; k0 < 512; k0 += 32) {
        bf16x8 a0 = *reinterpret_cast<const bf16x8*>(pa0 + k0);
        bf16x8 a1 = *reinterpret_cast<const bf16x8*>(pa1 + k0);
        bf16x8 b0 = *reinterpret_cast<const bf16x8*>(pb + k0);
        bf16x8 b1 = *reinterpret_cast<const bf16x8*>(pb + 16 * SMALL + k0);
        bf16x8 b2 = *reinterpret_cast<const bf16x8*>(pb + 32 * SMALL + k0);
        bf16x8 b3 = *reinterpret_cast<const bf16x8*>(pb + 48 * SMALL + k0);
        acc[0][0] = __builtin_amdgcn_mfma_f32_16x16x32_bf16(a0, b0, acc[0][0], 0, 0, 0);
        acc[0][1] = __builtin_amdgcn_mfma_f32_16x16x32_bf16(a0, b1, acc[0][1], 0, 0, 0);
        acc[0][2] = __builtin_amdgcn_mfma_f32_16x16x32_bf16(a0, b2, acc[0][2], 0, 0, 0);
        acc[0][3] = __builtin_amdgcn_mfma_f32_16x16x32_bf16(a0, b3, acc[0][3], 0, 0, 0);
        acc[1][0] = __builtin_amdgcn_mfma_f32_16x16x32_bf16(a1, b0, acc[1][0], 0, 0, 0);
        acc[1][1] = __builtin_amdgcn_mfma_f32_16x16x32_bf16(a1, b1, acc[1][1], 0, 0, 0);
        acc[1][2] = __builtin_amdgcn_mfma_f32_16x16x32_bf16(a1, b2, acc[1][2], 0, 0, 0);
        acc[1][3] = __builtin_amdgcn_mfma_f32_16x16x32_bf16(a1, b3, acc[1][3], 0, 0, 0);
    }

    // Epilogue: C/D layout: col = lane&15, row = (lane>>4)*4 + reg   [guide §3, m89]
    const int rbase = row0 + (lane >> 4) * 4;
    const int cbase = SMALL + col0 + lr;
#pragma unroll
    for (int m = 0; m < 2; ++m) {
#pragma unroll
        for (int r = 0; r < 4; ++r) {
            const int row = rbase + m * 16 + r;
            const int id  = ids[row];
            const float* res = residual + (size_t)id * LARGE + cbase;
            float*       op  = out      + (size_t)row * LARGE + cbase;
#pragma unroll
            for (int n = 0; n < 4; ++n)
                op[n * 16] = acc[m][n][r] + res[n * 16];
        }
    }
}

extern "C" void kernel_launch(void* const* d_in, const int* in_sizes, int n_in,
                              void* d_out, int out_size, void* d_ws, size_t ws_size,
                              hipStream_t stream) {
    const int*   ids      = (const int*)d_in[0];
    const float* weight   = (const float*)d_in[1];
    const float* coeffs   = (const float*)d_in[2];
    const float* residual = (const float*)d_in[3];
    float*       out      = (float*)d_out;

    unsigned short* a_bf16 = (unsigned short*)d_ws;                       // 8192*512*2 = 8 MB
    unsigned short* b_bf16 = (unsigned short*)((char*)d_ws + (size_t)NTOK * SMALL * 2);  // 512 KB

    // Kernel 1: NTOK tokens * 128 threads = 1,048,576 threads
    k_gather<<<(NTOK * 128) / 256, 256, 0, stream>>>(ids, weight, residual, out, a_bf16);
    // Kernel 2: 512*512/4 = 65536 threads
    k_cvt_coeffs<<<(512 * 128) / 256, 256, 0, stream>>>(coeffs, b_bf16);
    // Kernel 3: (8192/128) * (512/64) = 64*8 = 512 blocks
    k_gemm<<<512, 256, 0, stream>>>(ids, a_bf16, b_bf16, residual, out);
}